// Round 14
// baseline (210.330 us; speedup 1.0000x reference)
//
#include <hip/hip_runtime.h>
#include <hip/hip_bf16.h>
#include <stdint.h>

#define NPTS 131072
#define DIM  512
#define KC   512
#define BM   128
#define BK   16
#define NKT  32          // DIM / BK

typedef float f32x16 __attribute__((ext_vector_type(16)));
typedef float f32x4  __attribute__((ext_vector_type(4)));
typedef short bf16x8 __attribute__((ext_vector_type(8)));

__device__ __forceinline__ float sq4(f32x4 a) {
  return a.x*a.x + a.y*a.y + a.z*a.z + a.w*a.w;
}

// packed RNE fp32->bf16 (v_cvt_pk_bf16_f32)
__device__ __forceinline__ bf16x8 pack8c(f32x4 a, f32x4 b) {
  union { __hip_bfloat162 h; short s[2]; } u0, u1, u2, u3;
  u0.h = __float22bfloat162_rn(make_float2(a.x, a.y));
  u1.h = __float22bfloat162_rn(make_float2(a.z, a.w));
  u2.h = __float22bfloat162_rn(make_float2(b.x, b.y));
  u3.h = __float22bfloat162_rn(make_float2(b.z, b.w));
  bf16x8 r;
  r[0] = u0.s[0]; r[1] = u0.s[1]; r[2] = u1.s[0]; r[3] = u1.s[1];
  r[4] = u2.s[0]; r[5] = u2.s[1]; r[6] = u3.s[0]; r[7] = u3.s[1];
  return r;
}

// scalar RNE (cluster pre-kernel only)
__device__ __forceinline__ short f2bf(float f) {
  union { float f; unsigned u; } v; v.f = f;
  unsigned r = v.u + 0x7FFFu + ((v.u >> 16) & 1u);
  return (short)(r >> 16);
}
__device__ __forceinline__ bf16x8 pack8(f32x4 a, f32x4 b) {
  bf16x8 p;
  p[0] = f2bf(a.x); p[1] = f2bf(a.y); p[2] = f2bf(a.z); p[3] = f2bf(a.w);
  p[4] = f2bf(b.x); p[5] = f2bf(b.y); p[6] = f2bf(b.z); p[7] = f2bf(b.w);
  return p;
}

__device__ __forceinline__ void gload_lds16(const void* g, void* l) {
  __builtin_amdgcn_global_load_lds(
      (const __attribute__((address_space(1))) unsigned int*)g,
      (__attribute__((address_space(3))) unsigned int*)l, 16, 0, 0);
}

// ---------------------------------------------------------------------------
// Cluster pre-kernel (layout verified R5-R13, unchanged): fp32 [512][512] ->
// bf16 in MFMA-B-fragment order. Short offset = q*8192 + wn*2048 + nt*512 +
// (h*32+r)*8 where q = k/16 — each 16 KB q-tile contiguous (= one BK=16
// K-step tile), staged linearly, fragments read at base + lane*16.
// c2[n] = ||c_n||^2 fp32.
// ---------------------------------------------------------------------------
__global__ void dec_pack(const float* __restrict__ C, short* __restrict__ Bp,
                         float* __restrict__ c2) {
  const int n    = blockIdx.x;
  const int lane = threadIdx.x;
  const float* src = C + (size_t)n * DIM + lane * 8;
  f32x4 v0 = *(const f32x4*)src;
  f32x4 v1 = *(const f32x4*)(src + 4);
  float s = sq4(v0) + sq4(v1);
  #pragma unroll
  for (int m = 1; m < 64; m <<= 1) s += __shfl_xor(s, m, 64);
  if (lane == 0) c2[n] = s;
  const int kt = lane >> 2;
  const int st = (lane >> 1) & 1;
  const int hh = lane & 1;
  const int wn = n >> 7, nt = (n >> 5) & 3, r = n & 31;
  const size_t slot =
      (((size_t)(kt * 2 + st) * 4 + wn) * 4 + nt) * 64 + hh * 32 + r;
  *(bf16x8*)(Bp + slot * 8) = pack8(v0, v1);
}

// ---------------------------------------------------------------------------
// Main fused kernel (R14): BM=128, BK=16, 1 block/CU, ring-4 deep pipeline.
// 512 threads = 8 waves (wm = wave>>2 in {0,1}, wn = wave&3); block tile
// 128 x 512 (full cluster width). Wave tile 64 x 128: mt=2 x nt=4,
// acc = 8 x f32x16 (128 AGPR); 8 MFMA per phase per wave.
//
// 32 phases (one per BK=16 K-step). Phase kt:
//   [s_waitcnt vmcnt(6); s_barrier]            (buffers staged 3 phases ago
//                                               guaranteed landed; 2 phases
//                                               of loads stay in flight)
//   [stage kt+3 (clamped): B 2x gload_lds (8 KB each) + A 1x gload_lds
//    (8 KB fp32) into ring slot (kt+3)&3]
//   [compute kt from slot kt&3: per mt: 2x A-frag ds_read_b128 (chunk-XOR
//    (row&3), verified min-sweep conflict-free) -> cvt_pk; 4x B-frag
//    ds_read_b128 (linear); 8 MFMA; x2 fused from fp32 regs].
// A staging obeys the gload_lds lane*16 contract: thread t -> row t>>2,
// dest linear t*16B, source chunk (t&3)^(row&3) (XOR involution).
// LDS: B 4x16 KB + A 4x8 KB + epi 2.5 KB = 98.5 KB -> 1 block/CU;
// ~200 unified regs -> 2 waves/SIMD (exactly 8 waves resident).
// Tail phases stage clamped dead loads (into slots never read again) to
// keep vmcnt counts uniform; they drain at kernel end.
// ---------------------------------------------------------------------------
__global__ __launch_bounds__(512, 2)
void dec_main(const float* __restrict__ X, const short* __restrict__ Bp,
              const float* __restrict__ c2g, float* __restrict__ out) {
  __shared__ short Bh[4][8192];     // 4 x 16 KB B q-tiles (frag order)
  __shared__ float Ah[4][2048];     // 4 x 8 KB fp32 A tiles (chunk-swizzled)
  __shared__ float part[4][BM];     // epilogue scratch (separate; no overlay)
  __shared__ float rowinv[BM];

  const int tid  = threadIdx.x;
  const int lane = tid & 63;
  const int wave = tid >> 6;
  const int wm   = wave >> 2;   // 0..1 : row half (64 rows each)
  const int wn   = wave & 3;    // 0..3 : column quarter
  const int l31  = lane & 31;
  const int h    = lane >> 5;
  const int row0 = blockIdx.x * BM;

  // A staging (lane*16 contract): thread t -> row t>>2, dest chunk t&3 at
  // linear t*16B; source chunk = (t&3)^(row&3).
  const int art = tid >> 2;     // 0..127
  const int act = tid & 3;
  const float* asrc = X + (size_t)(row0 + art) * DIM +
                      ((act ^ (art & 3)) << 2);
  // B staging: 2 sweeps of 16 B/thread, linear (pre-packed source)
  const short* bsrc = Bp + tid * 8;

  const int asw = l31 & 3;      // read-side chunk XOR

  f32x16 acc[2][4];
  #pragma unroll
  for (int mt = 0; mt < 2; ++mt)
    #pragma unroll
    for (int nt = 0; nt < 4; ++nt) acc[mt][nt] = (f32x16)0.f;
  float x2s[2] = {0.f, 0.f};

  // ---- prologue: stage kt = 0, 1, 2 (3 ops each, 9 outstanding) ----
  #pragma unroll
  for (int k0 = 0; k0 < 3; ++k0) {
    gload_lds16(bsrc + (size_t)k0 * 8192, &Bh[k0][tid * 8]);
    gload_lds16(bsrc + (size_t)k0 * 8192 + 4096, &Bh[k0][4096 + tid * 8]);
    gload_lds16(asrc + k0 * BK, &Ah[k0][tid * 4]);
    __builtin_amdgcn_sched_barrier(0);
  }

  // ---- K loop: 32 phases, one barrier each, counted vmcnt ----
  for (int kt = 0; kt < NKT; ++kt) {
    const int sl = kt & 3;            // consume slot
    const int st = (kt + 3) & 3;      // stage slot (free: consumed at kt-1)

    asm volatile("s_waitcnt vmcnt(6)" ::: "memory");
    __builtin_amdgcn_sched_barrier(0);
    __builtin_amdgcn_s_barrier();
    __builtin_amdgcn_sched_barrier(0);
    {
      const int qs = (kt + 3 < NKT) ? kt + 3 : NKT - 1;   // clamped (dead ok)
      gload_lds16(bsrc + (size_t)qs * 8192, &Bh[st][tid * 8]);
      gload_lds16(bsrc + (size_t)qs * 8192 + 4096, &Bh[st][4096 + tid * 8]);
      gload_lds16(asrc + qs * BK, &Ah[st][tid * 4]);
    }
    __builtin_amdgcn_sched_barrier(0);
    {
      const float* A  = &Ah[sl][0];
      const short* Bt = &Bh[sl][0];
      bf16x8 af[2];
      #pragma unroll
      for (int mt = 0; mt < 2; ++mt) {
        const int rrb = (wm * 64 + mt * 32 + l31) * 16;   // floats
        f32x4 lo = *(const f32x4*)&A[rrb + (((2 * h + 0) ^ asw) << 2)];
        f32x4 hi = *(const f32x4*)&A[rrb + (((2 * h + 1) ^ asw) << 2)];
        x2s[mt] += sq4(lo) + sq4(hi);
        af[mt] = pack8c(lo, hi);
      }
      bf16x8 bfr[4];
      #pragma unroll
      for (int nt = 0; nt < 4; ++nt)
        bfr[nt] = *(const bf16x8*)&Bt[(wn * 4 + nt) * 512 + lane * 8];
      #pragma unroll
      for (int mt = 0; mt < 2; ++mt)
        #pragma unroll
        for (int nt = 0; nt < 4; ++nt)
          acc[mt][nt] = __builtin_amdgcn_mfma_f32_32x32x16_bf16(
              af[mt], bfr[nt], acc[mt][nt], 0, 0, 0);
    }
  }

  // ---- x2: combine the two k-halves; lane l31 holds rows wm*64+mt*32+l31 ----
  #pragma unroll
  for (int mt = 0; mt < 2; ++mt) x2s[mt] += __shfl_xor(x2s[mt], 32, 64);

  float c2v[4];
  #pragma unroll
  for (int nt = 0; nt < 4; ++nt) c2v[nt] = c2g[wn * 128 + nt * 32 + l31];

  // ---- q = rcp(1+d2), per-row partial sums over this wave's 128 cols ----
  float srow[2][16];
  #pragma unroll
  for (int mt = 0; mt < 2; ++mt) {
    #pragma unroll
    for (int r = 0; r < 16; ++r) {
      const int mloc = (r & 3) + 8 * (r >> 2) + 4 * h;   // 0..31
      const float x2m = __shfl(x2s[mt], mloc, 64);
      float s = 0.f;
      #pragma unroll
      for (int nt = 0; nt < 4; ++nt) {
        float d2 = fmaxf(x2m + c2v[nt] - 2.f * acc[mt][nt][r], 0.f);
        float q = __builtin_amdgcn_rcpf(1.f + d2);
        acc[mt][nt][r] = q;
        s += q;
      }
      #pragma unroll
      for (int msk = 1; msk < 32; msk <<= 1) s += __shfl_xor(s, msk, 64);
      srow[mt][r] = s;
    }
  }

  if (l31 == 0) {
    #pragma unroll
    for (int mt = 0; mt < 2; ++mt)
      #pragma unroll
      for (int r = 0; r < 16; ++r)
        part[wn][wm * 64 + mt * 32 + (r & 3) + 8 * (r >> 2) + 4 * h] =
            srow[mt][r];
  }
  __syncthreads();
  if (tid < BM)
    rowinv[tid] = __builtin_amdgcn_rcpf(part[0][tid] + part[1][tid] +
                                        part[2][tid] + part[3][tid]);
  __syncthreads();

  // ---- normalize + coalesced stores (8 waves stream independently) ----
  #pragma unroll
  for (int mt = 0; mt < 2; ++mt) {
    #pragma unroll
    for (int r = 0; r < 16; ++r) {
      const int row = wm * 64 + mt * 32 + (r & 3) + 8 * (r >> 2) + 4 * h;
      const float iv = rowinv[row];
      float* o = out + (size_t)(row0 + row) * KC + wn * 128 + l31;
      #pragma unroll
      for (int nt = 0; nt < 4; ++nt)
        o[nt * 32] = acc[mt][nt][r] * iv;
    }
  }
}

extern "C" void kernel_launch(void* const* d_in, const int* in_sizes, int n_in,
                              void* d_out, int out_size, void* d_ws, size_t ws_size,
                              hipStream_t stream) {
  const float* X = (const float*)d_in[0];   // inputs  [131072, 512] fp32
  const float* C = (const float*)d_in[1];   // clusters [512, 512] fp32
  float* out = (float*)d_out;               // [131072, 512] fp32

  short* Bp = (short*)d_ws;                                   // 512 KB packed bf16 clusters
  float* c2 = (float*)((char*)d_ws + (size_t)KC * DIM * 2);   // 2 KB cluster norms

  dec_pack<<<KC, 64, 0, stream>>>(C, Bp, c2);
  dec_main<<<NPTS / BM, 512, 0, stream>>>(X, Bp, c2, out);
}